// Round 1
// baseline (22.696 us; speedup 1.0000x reference)
//
#include <hip/hip_runtime.h>
#include <math.h>

// PolyIoULoss: rotated-box IoU loss, N pairs, scalar mean output.
// One thread per pair: build both quads, Sutherland-Hodgman clip P against T
// (LDS ping-pong buffers for the runtime-indexed polygon), shoelace area,
// iou = max(area/(a1+a2-area+1e-6), 1e-6), loss = -log(iou).
// Deterministic two-stage reduction (no float atomics).

#define BS 256
#define SLOTS 9   // structural max polygon size is 8; +1 slack

struct F2 { float x, y; };

__global__ __launch_bounds__(BS) void poly_iou_kernel(
    const float* __restrict__ pred, const float* __restrict__ tgt,
    float* __restrict__ block_sums, int n)
{
    __shared__ F2 bufA[SLOTS][BS];
    __shared__ F2 bufB[SLOTS][BS];
    const int tid = threadIdx.x;
    const int gid = blockIdx.x * BS + tid;

    float loss = 0.0f;
    if (gid < n) {
        float pb[5], tb[5];
#pragma unroll
        for (int i = 0; i < 5; ++i) {
            pb[i] = pred[(long)gid * 5 + i];
            tb[i] = tgt[(long)gid * 5 + i];
        }

        // obb -> corners. Reference einsum gives:
        //   x' = cx + ox*cos + oy*sin ;  y' = cy - ox*sin + oy*cos   (CCW order)
        F2 P[4], T[4];
        {
            float s, c; sincosf(pb[4], &s, &c);
            const float dx = 0.5f * pb[2], dy = 0.5f * pb[3];
            const float ox[4] = {-dx, dx, dx, -dx};
            const float oy[4] = {-dy, -dy, dy, dy};
#pragma unroll
            for (int k = 0; k < 4; ++k) {
                P[k].x = pb[0] + ox[k] * c + oy[k] * s;
                P[k].y = pb[1] - ox[k] * s + oy[k] * c;
            }
        }
        {
            float s, c; sincosf(tb[4], &s, &c);
            const float dx = 0.5f * tb[2], dy = 0.5f * tb[3];
            const float ox[4] = {-dx, dx, dx, -dx};
            const float oy[4] = {-dy, -dy, dy, dy};
#pragma unroll
            for (int k = 0; k < 4; ++k) {
                T[k].x = tb[0] + ox[k] * c + oy[k] * s;
                T[k].y = tb[1] - ox[k] * s + oy[k] * c;
            }
        }

        // init subject polygon = P
#pragma unroll
        for (int k = 0; k < 4; ++k) bufA[k][tid] = P[k];
        int ncur = 4;
        F2 (*src)[BS] = bufA;
        F2 (*dst)[BS] = bufB;

        // clip against the 4 half-planes of T (inside: cross >= 0 for CCW)
#pragma unroll
        for (int e = 0; e < 4; ++e) {
            const F2 A = T[e];
            const F2 B = T[(e + 1) & 3];
            const float ex = B.x - A.x, ey = B.y - A.y;
            int m = 0;
            if (ncur > 1) {
                F2 C = src[0][tid];
                float dc = ex * (C.y - A.y) - ey * (C.x - A.x);
                const F2 v0 = C;
                const float d0 = dc;
                // input polygon for pass e has <= 4+e vertices (convex)
#pragma unroll
                for (int i = 0; i < 4 + e; ++i) {
                    if (i < ncur) {
                        F2 D; float dd;
                        if (i + 1 < ncur) {
                            D = src[i + 1][tid];
                            dd = ex * (D.y - A.y) - ey * (D.x - A.x);
                        } else { D = v0; dd = d0; }
                        const bool inC = dc >= 0.0f;
                        const bool inD = dd >= 0.0f;
                        if (inC) { dst[m][tid] = C; ++m; }
                        if (inC != inD) {
                            const float t = dc / (dc - dd);
                            F2 I;
                            I.x = C.x + t * (D.x - C.x);
                            I.y = C.y + t * (D.y - C.y);
                            dst[m][tid] = I; ++m;
                        }
                        C = D; dc = dd;
                    }
                }
            }
            ncur = m;
            F2 (*tmp)[BS] = src; src = dst; dst = tmp;
        }

        // shoelace over final polygon (<= 8 vertices)
        float area2 = 0.0f;
        if (ncur >= 3) {
            const F2 v0 = src[0][tid];
            F2 C = v0;
#pragma unroll
            for (int i = 0; i < 8; ++i) {
                if (i < ncur) {
                    F2 D;
                    if (i + 1 < ncur) D = src[i + 1][tid]; else D = v0;
                    area2 += C.x * D.y - D.x * C.y;
                    C = D;
                }
            }
        }
        const float area = 0.5f * fabsf(area2);
        const float a1 = pb[2] * pb[3];
        const float a2 = tb[2] * tb[3];
        const float iou = fmaxf(area / (a1 + a2 - area + 1e-6f), 1e-6f);
        loss = -logf(iou);
    }

    // block reduction (wave shuffle + tiny LDS), deterministic
#pragma unroll
    for (int off = 32; off > 0; off >>= 1) loss += __shfl_down(loss, off);
    __shared__ float wsum[BS / 64];
    if ((tid & 63) == 0) wsum[tid >> 6] = loss;
    __syncthreads();
    if (tid == 0) {
        float s = 0.0f;
#pragma unroll
        for (int w = 0; w < BS / 64; ++w) s += wsum[w];
        block_sums[blockIdx.x] = s;
    }
}

__global__ __launch_bounds__(BS) void poly_iou_reduce(
    const float* __restrict__ block_sums, int nblocks,
    float* __restrict__ out, double inv_n)
{
    const int tid = threadIdx.x;
    double s = 0.0;
    for (int i = tid; i < nblocks; i += BS) s += (double)block_sums[i];
#pragma unroll
    for (int off = 32; off > 0; off >>= 1) s += __shfl_down(s, off);
    __shared__ double ws[BS / 64];
    if ((tid & 63) == 0) ws[tid >> 6] = s;
    __syncthreads();
    if (tid == 0) {
        double tot = 0.0;
#pragma unroll
        for (int w = 0; w < BS / 64; ++w) tot += ws[w];
        out[0] = (float)(tot * inv_n);
    }
}

extern "C" void kernel_launch(void* const* d_in, const int* in_sizes, int n_in,
                              void* d_out, int out_size, void* d_ws, size_t ws_size,
                              hipStream_t stream) {
    const float* pred = (const float*)d_in[0];
    const float* tgt  = (const float*)d_in[1];
    float* out = (float*)d_out;
    const int n = in_sizes[0] / 5;
    const int nblocks = (n + BS - 1) / BS;
    float* bsums = (float*)d_ws;

    hipLaunchKernelGGL(poly_iou_kernel, dim3(nblocks), dim3(BS), 0, stream,
                       pred, tgt, bsums, n);
    hipLaunchKernelGGL(poly_iou_reduce, dim3(1), dim3(BS), 0, stream,
                       bsums, nblocks, out, 1.0 / (double)n);
}

// Round 2
// 21.335 us; speedup vs baseline: 1.0638x; 1.0638x over previous
//
#include <hip/hip_runtime.h>
#include <math.h>

// PolyIoULoss: rotated-box IoU loss via Green's theorem.
// Area(P ∩ T) = 0.5 * [ sum over P-edges clipped to T of cross(A',B')
//                     + sum over T-edges clipped to P of cross(A',B') ].
// Segment-vs-convex-quad clipping is a branchless parametric interval clamp:
// no polygon construction, no dynamic indexing, no divergence.
// Deterministic two-stage reduction (no float atomics).

#define BS 256

__global__ __launch_bounds__(BS) void poly_iou_kernel(
    const float* __restrict__ pred, const float* __restrict__ tgt,
    float* __restrict__ block_sums, int n)
{
    __shared__ float sP[BS * 5];
    __shared__ float sT[BS * 5];
    const int tid = threadIdx.x;
    const int gid = blockIdx.x * BS + tid;

    // coalesced staging of this block's boxes (stride-20B per thread otherwise)
    {
        const long base = (long)blockIdx.x * (BS * 5);
        const long tot = (long)n * 5;
#pragma unroll
        for (int j = 0; j < 5; ++j) {
            const int idx = j * BS + tid;
            const long g = base + idx;
            if (g < tot) { sP[idx] = pred[g]; sT[idx] = tgt[g]; }
        }
    }
    __syncthreads();

    float loss = 0.0f;
    if (gid < n) {
        const float pcx = sP[tid * 5 + 0], pcy = sP[tid * 5 + 1];
        const float pw  = sP[tid * 5 + 2], ph  = sP[tid * 5 + 3];
        const float pth = sP[tid * 5 + 4];
        // shift everything by pred center: coords ~O(50) instead of O(500)
        const float tcx = sT[tid * 5 + 0] - pcx, tcy = sT[tid * 5 + 1] - pcy;
        const float tw  = sT[tid * 5 + 2], th_  = sT[tid * 5 + 3];
        const float tth = sT[tid * 5 + 4];

        // Reference einsum: x' = cx + ox*cos + oy*sin ; y' = cy - ox*sin + oy*cos
        // corner order (-dx,-dy),(dx,-dy),(dx,dy),(-dx,dy) -> CCW preserved.
        float px[4], py[4], tx[4], ty[4];
        {
            float s, c; __sincosf(pth, &s, &c);
            const float dx = 0.5f * pw, dy = 0.5f * ph;
            const float xc = dx * c, xs = dx * s, yc = dy * c, ys = dy * s;
            px[0] = -(xc + ys); py[0] = xs - yc;
            px[1] = xc - ys;    py[1] = -(xs + yc);
            px[2] = xc + ys;    py[2] = yc - xs;
            px[3] = ys - xc;    py[3] = xs + yc;
        }
        {
            float s, c; __sincosf(tth, &s, &c);
            const float dx = 0.5f * tw, dy = 0.5f * th_;
            const float xc = dx * c, xs = dx * s, yc = dy * c, ys = dy * s;
            tx[0] = tcx - (xc + ys); ty[0] = tcy + xs - yc;
            tx[1] = tcx + xc - ys;   ty[1] = tcy - (xs + yc);
            tx[2] = tcx + xc + ys;   ty[2] = tcy + yc - xs;
            tx[3] = tcx + ys - xc;   ty[3] = tcy + xs + yc;
        }

        // edge vectors
        float pex[4], pey[4], tex[4], tey[4];
#pragma unroll
        for (int k = 0; k < 4; ++k) {
            const int k1 = (k + 1) & 3;
            pex[k] = px[k1] - px[k]; pey[k] = py[k1] - py[k];
            tex[k] = tx[k1] - tx[k]; tey[k] = ty[k1] - ty[k];
        }

        // plane-distance tables (each value reused by the two incident edges)
        // GP[i][k] = cross(T_edge[k], P[i] - T[k]) ; GT[i][k] = cross(P_edge[k], T[i] - P[k])
        float GP[4][4], GT[4][4];
#pragma unroll
        for (int i = 0; i < 4; ++i) {
#pragma unroll
            for (int k = 0; k < 4; ++k) {
                GP[i][k] = tex[k] * (py[i] - ty[k]) - tey[k] * (px[i] - tx[k]);
                GT[i][k] = pex[k] * (ty[i] - py[k]) - pey[k] * (tx[i] - px[k]);
            }
        }

        float acc = 0.0f;

        // P edges clipped to T
#pragma unroll
        for (int i = 0; i < 4; ++i) {
            const int i1 = (i + 1) & 3;
            const float Ax = px[i], Ay = py[i];
            const float rx = pex[i], ry = pey[i];
            float t0 = 0.0f, t1 = 1.0f;
#pragma unroll
            for (int k = 0; k < 4; ++k) {
                const float g0 = GP[i][k], g1 = GP[i1][k];
                const float dg = g1 - g0;
                const bool safe = fabsf(dg) >= 1e-9f;
                const float th = -g0 * __builtin_amdgcn_rcpf(safe ? dg : 1.0f);
                t0 = (safe && dg > 0.0f) ? fmaxf(t0, th) : t0;
                t1 = (safe && dg < 0.0f) ? fminf(t1, th) : t1;
                t0 = (!safe && g0 < 0.0f) ? 2.0f : t0;   // parallel & outside -> empty
            }
            const float Apx = fmaf(t0, rx, Ax), Apy = fmaf(t0, ry, Ay);
            const float Bpx = fmaf(t1, rx, Ax), Bpy = fmaf(t1, ry, Ay);
            acc += (t1 > t0) ? (Apx * Bpy - Bpx * Apy) : 0.0f;
        }

        // T edges clipped to P
#pragma unroll
        for (int i = 0; i < 4; ++i) {
            const int i1 = (i + 1) & 3;
            const float Ax = tx[i], Ay = ty[i];
            const float rx = tex[i], ry = tey[i];
            float t0 = 0.0f, t1 = 1.0f;
#pragma unroll
            for (int k = 0; k < 4; ++k) {
                const float g0 = GT[i][k], g1 = GT[i1][k];
                const float dg = g1 - g0;
                const bool safe = fabsf(dg) >= 1e-9f;
                const float th = -g0 * __builtin_amdgcn_rcpf(safe ? dg : 1.0f);
                t0 = (safe && dg > 0.0f) ? fmaxf(t0, th) : t0;
                t1 = (safe && dg < 0.0f) ? fminf(t1, th) : t1;
                t0 = (!safe && g0 < 0.0f) ? 2.0f : t0;
            }
            const float Apx = fmaf(t0, rx, Ax), Apy = fmaf(t0, ry, Ay);
            const float Bpx = fmaf(t1, rx, Ax), Bpy = fmaf(t1, ry, Ay);
            acc += (t1 > t0) ? (Apx * Bpy - Bpx * Apy) : 0.0f;
        }

        const float area = fmaxf(0.5f * acc, 0.0f);
        const float a1 = pw * ph;
        const float a2 = tw * th_;
        const float iou = fmaxf(area / (a1 + a2 - area + 1e-6f), 1e-6f);
        loss = -__logf(iou);
    }

    // block reduction (wave shuffle + tiny LDS), deterministic
#pragma unroll
    for (int off = 32; off > 0; off >>= 1) loss += __shfl_down(loss, off);
    __shared__ float wsum[BS / 64];
    if ((tid & 63) == 0) wsum[tid >> 6] = loss;
    __syncthreads();
    if (tid == 0) {
        float s = 0.0f;
#pragma unroll
        for (int w = 0; w < BS / 64; ++w) s += wsum[w];
        block_sums[blockIdx.x] = s;
    }
}

__global__ __launch_bounds__(BS) void poly_iou_reduce(
    const float* __restrict__ block_sums, int nblocks,
    float* __restrict__ out, double inv_n)
{
    const int tid = threadIdx.x;
    double s = 0.0;
    for (int i = tid; i < nblocks; i += BS) s += (double)block_sums[i];
#pragma unroll
    for (int off = 32; off > 0; off >>= 1) s += __shfl_down(s, off);
    __shared__ double ws[BS / 64];
    if ((tid & 63) == 0) ws[tid >> 6] = s;
    __syncthreads();
    if (tid == 0) {
        double tot = 0.0;
#pragma unroll
        for (int w = 0; w < BS / 64; ++w) tot += ws[w];
        out[0] = (float)(tot * inv_n);
    }
}

extern "C" void kernel_launch(void* const* d_in, const int* in_sizes, int n_in,
                              void* d_out, int out_size, void* d_ws, size_t ws_size,
                              hipStream_t stream) {
    const float* pred = (const float*)d_in[0];
    const float* tgt  = (const float*)d_in[1];
    float* out = (float*)d_out;
    const int n = in_sizes[0] / 5;
    const int nblocks = (n + BS - 1) / BS;
    float* bsums = (float*)d_ws;

    hipLaunchKernelGGL(poly_iou_kernel, dim3(nblocks), dim3(BS), 0, stream,
                       pred, tgt, bsums, n);
    hipLaunchKernelGGL(poly_iou_reduce, dim3(1), dim3(BS), 0, stream,
                       bsums, nblocks, out, 1.0 / (double)n);
}

// Round 3
// 15.167 us; speedup vs baseline: 1.4965x; 1.4067x over previous
//
#include <hip/hip_runtime.h>
#include <math.h>

// PolyIoULoss closed-form:
// Area(P∩T) via Green's theorem over clipped edges, where each edge's
// contribution is (t1-t0)*cross(A,r) and cross(A,r) collapses to per-box
// constants (+ offset corrections = components of R(psi)*tc).
// t0/t1 come from Liang-Barsky against an AABB in the other box's local
// frame (clip params are frame-invariant). Branchless; IEEE inf handles
// parallel edges. Deterministic two-stage reduction.

#define BS 256

__device__ __forceinline__ float lb_delta(float Ax, float Ay,
                                          float irx, float iry,
                                          float hw, float hh)
{
    // Liang-Barsky span of segment A + t*r, t in [0,1], vs |x|<=hw,|y|<=hh
    const float tA = (-hw - Ax) * irx;
    const float tB = ( hw - Ax) * irx;
    const float tC = (-hh - Ay) * iry;
    const float tD = ( hh - Ay) * iry;
    const float tx0 = fminf(tA, tB), tx1 = fmaxf(tA, tB);
    const float ty0 = fminf(tC, tD), ty1 = fmaxf(tC, tD);
    const float t0 = fmaxf(fmaxf(tx0, ty0), 0.0f);   // v_max3
    const float t1 = fminf(fminf(tx1, ty1), 1.0f);   // v_min3
    return fmaxf(t1 - t0, 0.0f);
}

__global__ __launch_bounds__(BS) void poly_iou_kernel(
    const float* __restrict__ pred, const float* __restrict__ tgt,
    float* __restrict__ block_sums, int n)
{
    const int tid = threadIdx.x;
    const int gid = blockIdx.x * BS + tid;

    float loss = 0.0f;
    if (gid < n) {
        const float* pp = pred + (long)gid * 5;
        const float* tp = tgt  + (long)gid * 5;
        const float pcx = pp[0], pcy = pp[1], pw = pp[2], ph = pp[3], phi = pp[4];
        const float tcx = tp[0] - pcx, tcy = tp[1] - pcy;   // pred-centered frame
        const float tw = tp[2], th = tp[3], psi = tp[4];

        const float a1 = 0.5f * pw, b1 = 0.5f * ph;
        const float a2 = 0.5f * tw, b2 = 0.5f * th;

        float sphi, cphi, spsi, cpsi;
        __sincosf(phi, &sphi, &cphi);
        __sincosf(psi, &spsi, &cpsi);
        // delta = psi - phi
        const float cd = cpsi * cphi + spsi * sphi;
        const float sd = spsi * cphi - cpsi * sphi;

        // ---- P edges in T-local frame; clipper AABB (a2,b2) ----
        // C = R(psi)*tc ; P corners = s1*X + s2*Y - C, X=a1*(cd,sd), Y=b1*(-sd,cd)
        const float Cx = cpsi * tcx - spsi * tcy;
        const float Cy = spsi * tcx + cpsi * tcy;
        const float Xx = a1 * cd,  Xy = a1 * sd;
        const float Yx = -b1 * sd, Yy = b1 * cd;
        const float i0x = __builtin_amdgcn_rcpf(2.0f * Xx);
        const float i0y = __builtin_amdgcn_rcpf(2.0f * Xy);
        const float i1x = __builtin_amdgcn_rcpf(2.0f * Yx);
        const float i1y = __builtin_amdgcn_rcpf(2.0f * Yy);

        const float dP0 = lb_delta(-Xx - Yx - Cx, -Xy - Yy - Cy,  i0x,  i0y, a2, b2);
        const float dP1 = lb_delta( Xx - Yx - Cx,  Xy - Yy - Cy,  i1x,  i1y, a2, b2);
        const float dP2 = lb_delta( Xx + Yx - Cx,  Xy + Yy - Cy, -i0x, -i0y, a2, b2);
        const float dP3 = lb_delta(-Xx + Yx - Cx, -Xy + Yy - Cy, -i1x, -i1y, a2, b2);
        const float sumP = (dP0 + dP1) + (dP2 + dP3);

        // ---- T edges in P-local frame; clipper AABB (a1,b1) ----
        // C2 = R(phi)*tc ; T corners = C2 + s1*Xp + s2*Yp,
        // Xp=a2*(cd,-sd), Yp=b2*(sd,cd)
        const float C2x = cphi * tcx - sphi * tcy;
        const float C2y = sphi * tcx + cphi * tcy;
        const float Xpx = a2 * cd,  Xpy = -a2 * sd;
        const float Ypx = b2 * sd,  Ypy = b2 * cd;
        const float j0x = __builtin_amdgcn_rcpf(2.0f * Xpx);
        const float j0y = __builtin_amdgcn_rcpf(2.0f * Xpy);
        const float j1x = __builtin_amdgcn_rcpf(2.0f * Ypx);
        const float j1y = __builtin_amdgcn_rcpf(2.0f * Ypy);

        const float dT0 = lb_delta(C2x - Xpx - Ypx, C2y - Xpy - Ypy,  j0x,  j0y, a1, b1);
        const float dT1 = lb_delta(C2x + Xpx - Ypx, C2y + Xpy - Ypy,  j1x,  j1y, a1, b1);
        const float dT2 = lb_delta(C2x + Xpx + Ypx, C2y + Xpy + Ypy, -j0x, -j0y, a1, b1);
        const float dT3 = lb_delta(C2x - Xpx + Ypx, C2y - Xpy + Ypy, -j1x, -j1y, a1, b1);
        const float sumT = (dT0 + dT1) + (dT2 + dT3);

        // Area = a1b1*sumP + a2b2*sumT + a2*(tc x u_t)*(dT0-dT2) + b2*(tc x v_t)*(dT1-dT3)
        // with tc x u_t = -Cy, tc x v_t = Cx.
        float area = a1 * b1 * sumP + a2 * b2 * sumT
                   - a2 * Cy * (dT0 - dT2) + b2 * Cx * (dT1 - dT3);
        area = fmaxf(area, 0.0f);

        const float A1 = pw * ph, A2 = tw * th;
        const float iou = fmaxf(area / (A1 + A2 - area + 1e-6f), 1e-6f);
        loss = -__logf(iou);
    }

    // block reduction (wave shuffle + tiny LDS), deterministic
#pragma unroll
    for (int off = 32; off > 0; off >>= 1) loss += __shfl_down(loss, off);
    __shared__ float wsum[BS / 64];
    if ((tid & 63) == 0) wsum[tid >> 6] = loss;
    __syncthreads();
    if (tid == 0) {
        float s = 0.0f;
#pragma unroll
        for (int w = 0; w < BS / 64; ++w) s += wsum[w];
        block_sums[blockIdx.x] = s;
    }
}

__global__ __launch_bounds__(BS) void poly_iou_reduce(
    const float* __restrict__ block_sums, int nblocks,
    float* __restrict__ out, double inv_n)
{
    const int tid = threadIdx.x;
    double s = 0.0;
    for (int i = tid; i < nblocks; i += BS) s += (double)block_sums[i];
#pragma unroll
    for (int off = 32; off > 0; off >>= 1) s += __shfl_down(s, off);
    __shared__ double ws[BS / 64];
    if ((tid & 63) == 0) ws[tid >> 6] = s;
    __syncthreads();
    if (tid == 0) {
        double tot = 0.0;
#pragma unroll
        for (int w = 0; w < BS / 64; ++w) tot += ws[w];
        out[0] = (float)(tot * inv_n);
    }
}

extern "C" void kernel_launch(void* const* d_in, const int* in_sizes, int n_in,
                              void* d_out, int out_size, void* d_ws, size_t ws_size,
                              hipStream_t stream) {
    const float* pred = (const float*)d_in[0];
    const float* tgt  = (const float*)d_in[1];
    float* out = (float*)d_out;
    const int n = in_sizes[0] / 5;
    const int nblocks = (n + BS - 1) / BS;
    float* bsums = (float*)d_ws;

    hipLaunchKernelGGL(poly_iou_kernel, dim3(nblocks), dim3(BS), 0, stream,
                       pred, tgt, bsums, n);
    hipLaunchKernelGGL(poly_iou_reduce, dim3(1), dim3(BS), 0, stream,
                       bsums, nblocks, out, 1.0 / (double)n);
}